// Round 2
// baseline (64.010 us; speedup 1.0000x reference)
//
#include <hip/hip_runtime.h>

#define FH 50
#define FW 50
#define FC 512
#define NROI 1024
#define HALF 256            // channels per block (512 split in 2)
#define COLS 15             // max distinct feature cols per (roi,py): 13*sx<=12.25 -> 15 slots
#define ROWS 3              // max distinct feature rows per (roi,py): sy<1 -> 3 slots
#define NEG_HUGE -3.402823466e+38f

__device__ __forceinline__ float4 blend4(float4 tl, float4 tr, float4 bl, float4 br,
                                         float w00, float w01, float w10, float w11) {
    float4 r;
    r.x = tl.x * w00 + tr.x * w01 + bl.x * w10 + br.x * w11;
    r.y = tl.y * w00 + tr.y * w01 + bl.y * w10 + br.y * w11;
    r.z = tl.z * w00 + tr.z * w01 + bl.z * w10 + br.z * w11;
    r.w = tl.w * w00 + tr.w * w01 + bl.w * w10 + br.w * w11;
    return r;
}

__device__ __forceinline__ void max4(float4& m, float4 v) {
    m.x = fmaxf(m.x, v.x);
    m.y = fmaxf(m.y, v.y);
    m.z = fmaxf(m.z, v.z);
    m.w = fmaxf(m.w, v.w);
}

// one block = (roi n, pooled row py, channel half). 256 threads = 4 waves.
// Stage the <=3x15 cell region of `feature` for this half into LDS, then each
// wave computes pooled pixels px = wave, wave+4 from LDS.
__global__ __launch_bounds__(256) void roi_pool_kernel(
    const float* __restrict__ feature,   // (1,50,50,512)
    const float* __restrict__ rois,      // (1024,4)
    const int*   __restrict__ img_size,  // (2)
    float*       __restrict__ out)       // (1024,7,7,512)
{
    __shared__ float lds[ROWS * COLS * HALF];   // 46080 B -> 3 blocks/CU

    int bid  = blockIdx.x;
    int n    = bid / 14;
    int rem  = bid - n * 14;
    int py   = rem >> 1;
    int half = rem & 1;

    int tid  = threadIdx.x;
    int wave = tid >> 6;
    int lane = tid & 63;

    float ih = (float)img_size[0];
    float iw = (float)img_size[1];
    float4 rv = *reinterpret_cast<const float4*>(rois + (size_t)n * 4);
    float x1 = rv.x / iw, y1 = rv.y / ih, x2 = rv.z / iw, y2 = rv.w / ih;

    const float HM1 = 49.0f, WM1 = 49.0f;
    float sy = (y2 - y1) * HM1 / 13.0f;   // < 1 for this input distribution
    float sx = (x2 - x1) * WM1 / 13.0f;   // < 1
    float oy = y1 * HM1;
    float ox = x1 * WM1;

    // y geometry (fixed for the whole block)
    float iy0 = oy + (float)(2 * py)     * sy;
    float iy1 = oy + (float)(2 * py + 1) * sy;
    float fy0 = floorf(iy0), fy1 = floorf(iy1);
    int   r0u = (int)fy0;
    int   tu1 = (int)fy1;                 // in {r0u, r0u+1}
    int   nrows = tu1 + 2 - r0u;          // 2 or 3
    float lyA[2]  = { iy0 - fy0, iy1 - fy1 };
    int   slotT[2] = { 0, tu1 - r0u };
    bool  vyA[2]  = { (iy0 >= 0.0f) && (iy0 <= HM1), (iy1 >= 0.0f) && (iy1 <= HM1) };

    // x extent for this block
    int c0u = (int)floorf(ox);
    int lu_max = (int)floorf(ox + 13.0f * sx);
    int ncols = lu_max + 2 - c0u;         // <= 15

    // ---- stage region into LDS: nrows x ncols cells x HALF channels ----
    const float* fbase = feature + half * HALF;
    int nfl4 = ncols * 64;                // float4 slots per row
    for (int r = 0; r < nrows; ++r) {
        int srow = min(r0u + r, FH - 1);
        const float* rowp = fbase + (size_t)srow * (FW * FC);
        float* ldsrow = lds + r * (COLS * HALF);
        for (int t = tid; t < nfl4; t += 256) {
            int cc = t >> 6;              // col slot
            int l4 = t & 63;              // float4 index within cell
            int scol = min(c0u + cc, FW - 1);
            float4 v = *reinterpret_cast<const float4*>(rowp + (size_t)scol * FC + l4 * 4);
            *reinterpret_cast<float4*>(ldsrow + cc * HALF + l4 * 4) = v;
        }
    }
    __syncthreads();

    // ---- compute 7 pooled pixels from LDS ----
    for (int px = wave; px < 7; px += 4) {
        float ix0 = ox + (float)(2 * px)     * sx;
        float ix1 = ox + (float)(2 * px + 1) * sx;
        float fx0 = floorf(ix0), fx1 = floorf(ix1);
        float lxA[2] = { ix0 - fx0, ix1 - fx1 };
        int   colL[2] = { (int)fx0 - c0u, (int)fx1 - c0u };
        bool  vxA[2] = { (ix0 >= 0.0f) && (ix0 <= WM1), (ix1 >= 0.0f) && (ix1 <= WM1) };

        float4 m = make_float4(NEG_HUGE, NEG_HUGE, NEG_HUGE, NEG_HUGE);

#pragma unroll
        for (int dy = 0; dy < 2; ++dy) {
            float lyv = lyA[dy], omy = 1.0f - lyv;
            const float* pT = lds + slotT[dy] * (COLS * HALF) + lane * 4;
            const float* pB = pT + (COLS * HALF);
#pragma unroll
            for (int dx = 0; dx < 2; ++dx) {
                float lxv = lxA[dx], omx = 1.0f - lxv;
                int co = colL[dx] * HALF;
                float4 tl = *reinterpret_cast<const float4*>(pT + co);
                float4 tr = *reinterpret_cast<const float4*>(pT + co + HALF);
                float4 bl = *reinterpret_cast<const float4*>(pB + co);
                float4 br = *reinterpret_cast<const float4*>(pB + co + HALF);
                float w00 = omy * omx, w01 = omy * lxv;
                float w10 = lyv * omx, w11 = lyv * lxv;
                float4 s = blend4(tl, tr, bl, br, w00, w01, w10, w11);
                if (!(vyA[dy] && vxA[dx])) {
                    s = make_float4(0.f, 0.f, 0.f, 0.f);
                }
                max4(m, s);
            }
        }

        float* po = out + (size_t)(n * 49 + py * 7 + px) * FC + half * HALF + lane * 4;
        *reinterpret_cast<float4*>(po) = m;
    }
}

extern "C" void kernel_launch(void* const* d_in, const int* in_sizes, int n_in,
                              void* d_out, int out_size, void* d_ws, size_t ws_size,
                              hipStream_t stream) {
    const float* feature  = (const float*)d_in[0];
    const float* rois     = (const float*)d_in[1];
    const int*   img_size = (const int*)d_in[2];
    float* out = (float*)d_out;

    int blocks = NROI * 7 * 2;   // (roi, py, ch-half) = 14336
    roi_pool_kernel<<<blocks, 256, 0, stream>>>(feature, rois, img_size, out);
}

// Round 3
// 36.937 us; speedup vs baseline: 1.7329x; 1.7329x over previous
//
#include <hip/hip_runtime.h>

#define FH 50
#define FW 50
#define FC 512
#define NROI 1024
#define ROWPITCH (FW * FC)   // 25600 floats per feature row

__device__ __forceinline__ float4 lerp4(float4 a, float4 b, float t) {
    float4 r;
    r.x = fmaf(t, b.x - a.x, a.x);
    r.y = fmaf(t, b.y - a.y, a.y);
    r.z = fmaf(t, b.z - a.z, a.z);
    r.w = fmaf(t, b.w - a.w, a.w);
    return r;
}

__device__ __forceinline__ float4 max44(float4 a, float4 b) {
    float4 r;
    r.x = fmaxf(a.x, b.x);
    r.y = fmaxf(a.y, b.y);
    r.z = fmaxf(a.z, b.z);
    r.w = fmaxf(a.w, b.w);
    return r;
}

// One wave per (roi n, pooled row py, channel half). The wave walks the <=16
// distinct feature columns of its sample row pair left->right; each column is
// loaded once (2-4 rows), vertically lerped into 2 register values, and
// consumed by the 14 horizontal samples via (prev,cur) column-pair lerps.
__global__ __launch_bounds__(256) void roi_pool_kernel(
    const float* __restrict__ feature,   // (1,50,50,512)
    const float* __restrict__ rois,      // (1024,4)
    const int*   __restrict__ img_size,  // (2)
    float*       __restrict__ out)       // (1024,7,7,512)
{
    int wid  = (blockIdx.x * 256 + threadIdx.x) >> 6;
    wid = __builtin_amdgcn_readfirstlane(wid);   // wave-uniform -> SGPR
    int lane = threadIdx.x & 63;

    int n    = wid / 14;
    int rem  = wid - n * 14;
    int py   = rem >> 1;
    int half = rem & 1;

    float ih = (float)img_size[0];
    float iw = (float)img_size[1];
    const float* rp = rois + (size_t)n * 4;
    float x1 = rp[0] / iw, y1 = rp[1] / ih, x2 = rp[2] / iw, y2 = rp[3] / ih;

    const float HM1 = 49.0f, WM1 = 49.0f;
    float sy = (y2 - y1) * HM1 / 13.0f;   // < 1 for this distribution
    float sx = (x2 - x1) * WM1 / 13.0f;   // < 1
    float oy = y1 * HM1;
    float ox = x1 * WM1;

    // y geometry (uniform for the wave)
    float iy0 = oy + (float)(2 * py)     * sy;
    float iy1 = oy + (float)(2 * py + 1) * sy;
    float fy0 = floorf(iy0), fy1 = floorf(iy1);
    float ly0 = iy0 - fy0,   ly1 = iy1 - fy1;
    int t0 = min(max((int)fy0, 0), FH - 1);
    int b0 = min(max((int)fy0 + 1, 0), FH - 1);
    int t1 = min(max((int)fy1, 0), FH - 1);
    int b1 = min(max((int)fy1 + 1, 0), FH - 1);
    bool vy0 = (iy0 >= 0.0f) && (iy0 <= HM1);
    bool vy1 = (iy1 >= 0.0f) && (iy1 <= HM1);
    bool sameRows = (t1 == t0) && (b1 == b0);

    const float* fbase = feature + half * 256 + lane * 4;

    // load column c and vertically reduce to V0 (sample row 2py) and V1 (2py+1)
    auto loadcol = [&](int c, float4& V0, float4& V1) {
        c = min(max(c, 0), FW - 1);
        const float* p = fbase + (size_t)c * FC;
        float4 A = *reinterpret_cast<const float4*>(p + (size_t)t0 * ROWPITCH);
        float4 B = *reinterpret_cast<const float4*>(p + (size_t)b0 * ROWPITCH);
        V0 = lerp4(A, B, ly0);
        if (sameRows) {
            V1 = lerp4(A, B, ly1);
        } else {
            float4 C = *reinterpret_cast<const float4*>(p + (size_t)t1 * ROWPITCH);
            float4 D = *reinterpret_cast<const float4*>(p + (size_t)b1 * ROWPITCH);
            V1 = lerp4(C, D, ly1);
        }
    };

    float4 VA0, VA1, VB0, VB1;
    int curL = (int)floorf(ox);
    loadcol(curL,     VA0, VA1);
    loadcol(curL + 1, VB0, VB1);

    float* obase = out + ((size_t)n * 49 + (size_t)py * 7) * FC + half * 256 + lane * 4;

    float4 m = make_float4(0.f, 0.f, 0.f, 0.f);
#pragma unroll 2
    for (int j = 0; j < 14; ++j) {
        float ix = ox + (float)j * sx;
        float fx = floorf(ix);
        int   lj = (int)fx;
        float lx = ix - fx;
        while (lj > curL) {               // advance at most 1 per j (sx<1)
            ++curL;
            VA0 = VB0; VA1 = VB1;
            loadcol(curL + 1, VB0, VB1);
        }
        float4 s0 = lerp4(VA0, VB0, lx);
        float4 s1 = lerp4(VA1, VB1, lx);
        bool vx = (ix >= 0.0f) && (ix <= WM1);
        if (!(vx && vy0)) s0 = make_float4(0.f, 0.f, 0.f, 0.f);
        if (!(vx && vy1)) s1 = make_float4(0.f, 0.f, 0.f, 0.f);
        float4 s = max44(s0, s1);
        if (j & 1) {
            m = max44(m, s);
            __builtin_nontemporal_store(m.x, &obase[(size_t)(j >> 1) * FC + 0]);
            __builtin_nontemporal_store(m.y, &obase[(size_t)(j >> 1) * FC + 1]);
            __builtin_nontemporal_store(m.z, &obase[(size_t)(j >> 1) * FC + 2]);
            __builtin_nontemporal_store(m.w, &obase[(size_t)(j >> 1) * FC + 3]);
        } else {
            m = s;
        }
    }
}

extern "C" void kernel_launch(void* const* d_in, const int* in_sizes, int n_in,
                              void* d_out, int out_size, void* d_ws, size_t ws_size,
                              hipStream_t stream) {
    const float* feature  = (const float*)d_in[0];
    const float* rois     = (const float*)d_in[1];
    const int*   img_size = (const int*)d_in[2];
    float* out = (float*)d_out;

    // 1024 rois * 14 (py, half) waves = 14336 waves, 4 waves/block
    int blocks = NROI * 14 / 4;   // 3584
    roi_pool_kernel<<<blocks, 256, 0, stream>>>(feature, rois, img_size, out);
}